// Round 1
// baseline (461.554 us; speedup 1.0000x reference)
//
#include <hip/hip_runtime.h>
#include <hip/hip_bf16.h>
#include <math.h>

// MHSA: B=4, N=2048, D=1024, H=16, hd=64
// Pipeline: cvt(x) + transpose(Wqkv,Wproj) -> GEMM(qkv, scatter QKV) ->
//           flash attention -> GEMM(proj)

typedef __bf16 bf16;
typedef __bf16 bf16x4 __attribute__((ext_vector_type(4)));
typedef __bf16 bf16x8 __attribute__((ext_vector_type(8)));
typedef float f32x4 __attribute__((ext_vector_type(4)));

#define AS1(p) ((const __attribute__((address_space(1))) void*)(p))
#define AS3(p) ((__attribute__((address_space(3))) void*)(p))

__device__ __forceinline__ void async16(const void* g, void* l) {
    __builtin_amdgcn_global_load_lds(AS1(g), AS3(l), 16, 0, 0);
}

// ---------------- conversion kernels ----------------

__global__ void cvt_f32_bf16(const float* __restrict__ in, bf16* __restrict__ out, int n4) {
    int i = blockIdx.x * blockDim.x + threadIdx.x;
    if (i < n4) {
        float4 v = ((const float4*)in)[i];
        bf16x4 o;
        o.x = (bf16)v.x; o.y = (bf16)v.y; o.z = (bf16)v.z; o.w = (bf16)v.w;
        ((bf16x4*)out)[i] = o;
    }
}

// in: [K][N] f32 row-major  ->  out: [N][K] bf16 row-major
__global__ void transpose_cvt(const float* __restrict__ in, bf16* __restrict__ out, int K, int N) {
    __shared__ float t[32][33];
    const int n0 = blockIdx.x * 32, k0 = blockIdx.y * 32;
    const int tx = threadIdx.x, ty = threadIdx.y;  // 32 x 8
    #pragma unroll
    for (int j = 0; j < 32; j += 8)
        t[ty + j][tx] = in[(size_t)(k0 + ty + j) * N + n0 + tx];
    __syncthreads();
    #pragma unroll
    for (int j = 0; j < 32; j += 8)
        out[(size_t)(n0 + ty + j) * K + k0 + tx] = (bf16)t[tx][ty + j];
}

// ---------------- shared GEMM main loop (128x128 tile, BK=32) ----------------
// A: [M][K] bf16 row-major; Bt: [Ncols][K] bf16 row-major (B transposed)
// 256 threads = 4 waves in 2x2; each wave 64x64 (4x4 MFMA subtiles)

__device__ __forceinline__ void gemm_mainloop(const bf16* __restrict__ A,
                                              const bf16* __restrict__ Bt,
                                              int K, int m0, int n0,
                                              bf16* As, bf16* Bs, f32x4 acc[4][4]) {
    const int tid = threadIdx.x;
    const int wave = tid >> 6, lane = tid & 63;
    const int c = lane & 15, quad = lane >> 4;
    const int wm = (wave & 1) * 64, wn = (wave >> 1) * 64;

    const int ci0 = (wave * 2 + 0) * 64 + lane;
    const int ci1 = (wave * 2 + 1) * 64 + lane;
    const bf16* ga0 = A  + (size_t)(m0 + (ci0 >> 2)) * K + (ci0 & 3) * 8;
    const bf16* ga1 = A  + (size_t)(m0 + (ci1 >> 2)) * K + (ci1 & 3) * 8;
    const bf16* gb0 = Bt + (size_t)(n0 + (ci0 >> 2)) * K + (ci0 & 3) * 8;
    const bf16* gb1 = Bt + (size_t)(n0 + (ci1 >> 2)) * K + (ci1 & 3) * 8;
    bf16* la0 = As + (wave * 2 + 0) * 512;
    bf16* la1 = As + (wave * 2 + 1) * 512;
    bf16* lb0 = Bs + (wave * 2 + 0) * 512;
    bf16* lb1 = Bs + (wave * 2 + 1) * 512;

    for (int kt = 0; kt < K; kt += 32) {
        async16(ga0 + kt, la0);
        async16(ga1 + kt, la1);
        async16(gb0 + kt, lb0);
        async16(gb1 + kt, lb1);
        __syncthreads();  // drains vmcnt: staged data visible
        bf16x8 af[4], bfr[4];
        #pragma unroll
        for (int i = 0; i < 4; i++)
            af[i] = *(const bf16x8*)(As + (wm + i * 16 + c) * 32 + quad * 8);
        #pragma unroll
        for (int j = 0; j < 4; j++)
            bfr[j] = *(const bf16x8*)(Bs + (wn + j * 16 + c) * 32 + quad * 8);
        #pragma unroll
        for (int i = 0; i < 4; i++)
            #pragma unroll
            for (int j = 0; j < 4; j++)
                acc[i][j] = __builtin_amdgcn_mfma_f32_16x16x32_bf16(af[i], bfr[j], acc[i][j], 0, 0, 0);
        __syncthreads();  // protect LDS before next stage
    }
}

// ---------------- GEMM 1: qkv = x @ Wqkv + bqkv, scatter to Q/K/Vt ----------------
// Q,K: [B*H][N][hd] bf16 ; Vt: [B*H][hd][N] bf16

__global__ __launch_bounds__(256) void gemm_qkv(const bf16* __restrict__ A,
                                                const bf16* __restrict__ Bt,
                                                const float* __restrict__ bias,
                                                bf16* __restrict__ Qb,
                                                bf16* __restrict__ Kb,
                                                bf16* __restrict__ Vtb) {
    __shared__ __align__(16) bf16 As[128 * 32];
    __shared__ __align__(16) bf16 Bs[128 * 32];
    f32x4 acc[4][4] = {};
    const int m0 = blockIdx.x * 128, n0 = blockIdx.y * 128;
    gemm_mainloop(A, Bt, 1024, m0, n0, As, Bs, acc);

    const int tid = threadIdx.x;
    const int wave = tid >> 6, lane = tid & 63;
    const int c = lane & 15, quad = lane >> 4;
    const int wm = (wave & 1) * 64, wn = (wave >> 1) * 64;
    const int sel = n0 >> 10;  // 0=Q 1=K 2=V
    bf16* QK = (sel == 0) ? Qb : Kb;

    #pragma unroll
    for (int j = 0; j < 4; j++) {
        const int nfull = n0 + wn + j * 16 + c;
        const int nmod = nfull & 1023;
        const int h = nmod >> 6, e = nmod & 63;
        const float bv = bias[nfull];
        #pragma unroll
        for (int i = 0; i < 4; i++) {
            const int mbase = m0 + wm + i * 16 + quad * 4;  // global token row (4 consecutive)
            const int b = mbase >> 11, t = mbase & 2047;
            if (sel < 2) {
                bf16* dst = QK + (((size_t)(b * 16 + h) * 2048 + t) * 64 + e);
                #pragma unroll
                for (int r = 0; r < 4; r++)
                    dst[(size_t)r * 64] = (bf16)(acc[i][j][r] + bv);
            } else {
                bf16* dst = Vtb + ((size_t)(b * 16 + h) * 64 + e) * 2048 + t;
                bf16x4 v;
                v.x = (bf16)(acc[i][j][0] + bv);
                v.y = (bf16)(acc[i][j][1] + bv);
                v.z = (bf16)(acc[i][j][2] + bv);
                v.w = (bf16)(acc[i][j][3] + bv);
                *(bf16x4*)dst = v;  // 4 consecutive tokens, 8B aligned
            }
        }
    }
}

// ---------------- flash attention ----------------
// grid: (16 q-tiles, 64 bh). Each block: 128 q-rows; loop 16 KV tiles of 128 keys.
// Out: [B*N][D] bf16 (token-major), feature = h*64 + hd

__global__ __launch_bounds__(256) void attn_kernel(const bf16* __restrict__ Q,
                                                   const bf16* __restrict__ Kg,
                                                   const bf16* __restrict__ Vt,
                                                   bf16* __restrict__ Out) {
    __shared__ __align__(16) bf16 kbuf[128 * 64];      // Q tile first, then K tiles
    __shared__ __align__(16) bf16 vbuf[64 * 128];      // V^T tile [hd][key]
    __shared__ __align__(16) bf16 pbuf[4 * 32 * 64];   // per-wave P half-tile [32 q][64 key]

    const int qt = blockIdx.x, bh = blockIdx.y;
    const int tid = threadIdx.x;
    const int wave = tid >> 6, lane = tid & 63;
    const int c = lane & 15, quad = lane >> 4;

    const bf16* Qb = Q  + (size_t)bh * 2048 * 64;
    const bf16* Kb = Kg + (size_t)bh * 2048 * 64;
    const bf16* Vb = Vt + (size_t)bh * 64 * 2048;

    // ---- stage Q tile (contiguous 16KB) and pull fragments into registers ----
    #pragma unroll
    for (int t2 = 0; t2 < 4; t2++) {
        const int ci = (wave * 4 + t2) * 64 + lane;
        async16(Qb + (size_t)qt * 128 * 64 + ci * 8, kbuf + (wave * 4 + t2) * 512);
    }
    __syncthreads();
    bf16x8 qf[2][2];
    #pragma unroll
    for (int i = 0; i < 2; i++)
        #pragma unroll
        for (int ks = 0; ks < 2; ks++)
            qf[i][ks] = *(const bf16x8*)(kbuf + (wave * 32 + i * 16 + c) * 64 + ks * 32 + quad * 8);
    __syncthreads();  // all waves done reading Q from kbuf

    float mrow[2][4], lrow[2][4];
    f32x4 o[2][4] = {};
    #pragma unroll
    for (int i = 0; i < 2; i++)
        #pragma unroll
        for (int r = 0; r < 4; r++) { mrow[i][r] = -1e30f; lrow[i][r] = 0.f; }

    const float sc2 = 0.125f * 1.44269504088896340736f;  // scale * log2(e)

    for (int kv = 0; kv < 16; kv++) {
        // stage K tile (contiguous) and V^T tile (64 rows x 256B)
        #pragma unroll
        for (int t2 = 0; t2 < 4; t2++) {
            const int ci = (wave * 4 + t2) * 64 + lane;
            async16(Kb + (size_t)kv * 128 * 64 + ci * 8, kbuf + (wave * 4 + t2) * 512);
        }
        #pragma unroll
        for (int t2 = 0; t2 < 4; t2++) {
            const int ci = (wave * 4 + t2) * 64 + lane;
            const int r = ci >> 4, cc = ci & 15;
            async16(Vb + (size_t)r * 2048 + kv * 128 + cc * 8, vbuf + (wave * 4 + t2) * 512);
        }
        __syncthreads();

        // ---- S = Q K^T  (wave: 32 q-rows x 128 keys) ----
        f32x4 s[2][8] = {};
        #pragma unroll
        for (int j = 0; j < 8; j++) {
            #pragma unroll
            for (int ks = 0; ks < 2; ks++) {
                bf16x8 kf = *(const bf16x8*)(kbuf + (j * 16 + c) * 64 + ks * 32 + quad * 8);
                #pragma unroll
                for (int i = 0; i < 2; i++)
                    s[i][j] = __builtin_amdgcn_mfma_f32_16x16x32_bf16(qf[i][ks], kf, s[i][j], 0, 0, 0);
            }
        }

        // ---- online softmax (rows live across the 16 c-lanes of each quad) ----
        float alpha[2][4];
        #pragma unroll
        for (int i = 0; i < 2; i++) {
            #pragma unroll
            for (int r = 0; r < 4; r++) {
                float mx = s[i][0][r];
                #pragma unroll
                for (int j = 1; j < 8; j++) mx = fmaxf(mx, s[i][j][r]);
                #pragma unroll
                for (int d = 1; d < 16; d <<= 1) mx = fmaxf(mx, __shfl_xor(mx, d));
                const float mn = fmaxf(mrow[i][r], mx);
                const float a_ = exp2f((mrow[i][r] - mn) * sc2);
                mrow[i][r] = mn;
                alpha[i][r] = a_;
                float sum = 0.f;
                #pragma unroll
                for (int j = 0; j < 8; j++) {
                    const float p = exp2f((s[i][j][r] - mn) * sc2);
                    s[i][j][r] = p;
                    sum += p;
                }
                #pragma unroll
                for (int d = 1; d < 16; d <<= 1) sum += __shfl_xor(sum, d);
                lrow[i][r] = a_ * lrow[i][r] + sum;
            }
        }
        // rescale O
        #pragma unroll
        for (int i = 0; i < 2; i++)
            #pragma unroll
            for (int n2 = 0; n2 < 4; n2++)
                #pragma unroll
                for (int r = 0; r < 4; r++)
                    o[i][n2][r] *= alpha[i][r];

        // ---- PV in two 64-key halves (P: C-layout -> LDS -> A-layout) ----
        bf16* pw = pbuf + wave * 32 * 64;
        #pragma unroll
        for (int h2 = 0; h2 < 2; h2++) {
            #pragma unroll
            for (int i = 0; i < 2; i++)
                #pragma unroll
                for (int jj = 0; jj < 4; jj++)
                    #pragma unroll
                    for (int r = 0; r < 4; r++)
                        pw[(i * 16 + quad * 4 + r) * 64 + jj * 16 + c] = (bf16)s[i][h2 * 4 + jj][r];
            asm volatile("s_waitcnt lgkmcnt(0)" ::: "memory");
            #pragma unroll
            for (int ks = 0; ks < 2; ks++) {
                const int gks = h2 * 2 + ks;
                bf16x8 pf[2], vf[4];
                #pragma unroll
                for (int i = 0; i < 2; i++)
                    pf[i] = *(const bf16x8*)(pw + (i * 16 + c) * 64 + ks * 32 + quad * 8);
                #pragma unroll
                for (int n2 = 0; n2 < 4; n2++)
                    vf[n2] = *(const bf16x8*)(vbuf + (n2 * 16 + c) * 128 + gks * 32 + quad * 8);
                #pragma unroll
                for (int i = 0; i < 2; i++)
                    #pragma unroll
                    for (int n2 = 0; n2 < 4; n2++)
                        o[i][n2] = __builtin_amdgcn_mfma_f32_16x16x32_bf16(pf[i], vf[n2], o[i][n2], 0, 0, 0);
            }
            asm volatile("s_waitcnt lgkmcnt(0)" ::: "memory");  // reads done before next half's writes
        }
        __syncthreads();  // protect kbuf/vbuf before next stage
    }

    // ---- epilogue: O /= l, write token-major bf16 ----
    const int b = bh >> 4, h = bh & 15;
    #pragma unroll
    for (int i = 0; i < 2; i++) {
        #pragma unroll
        for (int r = 0; r < 4; r++) {
            const float inv = 1.f / lrow[i][r];
            const int token = b * 2048 + qt * 128 + wave * 32 + i * 16 + quad * 4 + r;
            #pragma unroll
            for (int n2 = 0; n2 < 4; n2++) {
                const int feat = h * 64 + n2 * 16 + c;
                Out[(size_t)token * 1024 + feat] = (bf16)(o[i][n2][r] * inv);
            }
        }
    }
}

// ---------------- GEMM 2: out = attn_out @ Wproj + bproj (fp32 out) ----------------

__global__ __launch_bounds__(256) void gemm_proj(const bf16* __restrict__ A,
                                                 const bf16* __restrict__ Bt,
                                                 const float* __restrict__ bias,
                                                 float* __restrict__ Out) {
    __shared__ __align__(16) bf16 As[128 * 32];
    __shared__ __align__(16) bf16 Bs[128 * 32];
    f32x4 acc[4][4] = {};
    const int m0 = blockIdx.x * 128, n0 = blockIdx.y * 128;
    gemm_mainloop(A, Bt, 1024, m0, n0, As, Bs, acc);

    const int tid = threadIdx.x;
    const int wave = tid >> 6, lane = tid & 63;
    const int c = lane & 15, quad = lane >> 4;
    const int wm = (wave & 1) * 64, wn = (wave >> 1) * 64;

    #pragma unroll
    for (int j = 0; j < 4; j++) {
        const int nn = n0 + wn + j * 16 + c;
        const float bv = bias[nn];
        #pragma unroll
        for (int i = 0; i < 4; i++) {
            const int m = m0 + wm + i * 16 + quad * 4;
            #pragma unroll
            for (int r = 0; r < 4; r++)
                Out[(size_t)(m + r) * 1024 + nn] = acc[i][j][r] + bv;
        }
    }
}

// ---------------- launch ----------------

extern "C" void kernel_launch(void* const* d_in, const int* in_sizes, int n_in,
                              void* d_out, int out_size, void* d_ws, size_t ws_size,
                              hipStream_t stream) {
    const float* x     = (const float*)d_in[0];
    const float* Wqkv  = (const float*)d_in[1];
    const float* bqkv  = (const float*)d_in[2];
    const float* Wproj = (const float*)d_in[3];
    const float* bproj = (const float*)d_in[4];
    float* out = (float*)d_out;

    char* ws = (char*)d_ws;
    bf16* xb     = (bf16*)(ws);                       // 16,777,216 B
    bf16* wqkvt  = (bf16*)(ws + 16777216);            //  6,291,456 B
    bf16* wprojt = (bf16*)(ws + 23068672);            //  2,097,152 B
    bf16* Qb     = (bf16*)(ws + 25165824);            // 16,777,216 B
    bf16* Kb     = (bf16*)(ws + 41943040);            // 16,777,216 B
    bf16* Vtb    = (bf16*)(ws + 58720256);            // 16,777,216 B
    bf16* attno  = xb;  // reuse: x_bf16 dead after gemm_qkv

    cvt_f32_bf16<<<8192, 256, 0, stream>>>(x, xb, 2097152);
    transpose_cvt<<<dim3(96, 32), dim3(32, 8), 0, stream>>>(Wqkv, wqkvt, 1024, 3072);
    transpose_cvt<<<dim3(32, 32), dim3(32, 8), 0, stream>>>(Wproj, wprojt, 1024, 1024);
    gemm_qkv<<<dim3(64, 24), 256, 0, stream>>>(xb, wqkvt, bqkv, Qb, Kb, Vtb);
    attn_kernel<<<dim3(16, 64), 256, 0, stream>>>(Qb, Kb, Vtb, attno);
    gemm_proj<<<dim3(64, 8), 256, 0, stream>>>(attno, wprojt, bproj, out);
}

// Round 2
// 441.191 us; speedup vs baseline: 1.0462x; 1.0462x over previous
//
#include <hip/hip_runtime.h>
#include <hip/hip_bf16.h>
#include <math.h>

// MHSA: B=4, N=2048, D=1024, H=16, hd=64
// Pipeline: cvt(x) + transpose(Wqkv,Wproj) -> GEMM(qkv, scatter QKV) ->
//           flash attention (LDS-free fragment loads) -> GEMM(proj)

typedef __bf16 bf16;
typedef __bf16 bf16x4 __attribute__((ext_vector_type(4)));
typedef __bf16 bf16x8 __attribute__((ext_vector_type(8)));
typedef float f32x4 __attribute__((ext_vector_type(4)));

#define AS1(p) ((const __attribute__((address_space(1))) void*)(p))
#define AS3(p) ((__attribute__((address_space(3))) void*)(p))

__device__ __forceinline__ void async16(const void* g, void* l) {
    __builtin_amdgcn_global_load_lds(AS1(g), AS3(l), 16, 0, 0);
}

// Q pre-scale: hd^-0.5 * log2(e) folded into Q at qkv epilogue
#define QSCALE 0.18033688011112042f

// ---------------- conversion kernels ----------------

__global__ void cvt_f32_bf16(const float* __restrict__ in, bf16* __restrict__ out, int n4) {
    int i = blockIdx.x * blockDim.x + threadIdx.x;
    if (i < n4) {
        float4 v = ((const float4*)in)[i];
        bf16x4 o;
        o.x = (bf16)v.x; o.y = (bf16)v.y; o.z = (bf16)v.z; o.w = (bf16)v.w;
        ((bf16x4*)out)[i] = o;
    }
}

// in: [K][N] f32 row-major  ->  out: [N][K] bf16 row-major
__global__ void transpose_cvt(const float* __restrict__ in, bf16* __restrict__ out, int K, int N) {
    __shared__ float t[32][33];
    const int n0 = blockIdx.x * 32, k0 = blockIdx.y * 32;
    const int tx = threadIdx.x, ty = threadIdx.y;  // 32 x 8
    #pragma unroll
    for (int j = 0; j < 32; j += 8)
        t[ty + j][tx] = in[(size_t)(k0 + ty + j) * N + n0 + tx];
    __syncthreads();
    #pragma unroll
    for (int j = 0; j < 32; j += 8)
        out[(size_t)(n0 + ty + j) * K + k0 + tx] = (bf16)t[tx][ty + j];
}

// ---------------- shared GEMM main loop (128x128 tile, BK=32) ----------------

__device__ __forceinline__ void gemm_mainloop(const bf16* __restrict__ A,
                                              const bf16* __restrict__ Bt,
                                              int K, int m0, int n0,
                                              bf16* As, bf16* Bs, f32x4 acc[4][4]) {
    const int tid = threadIdx.x;
    const int wave = tid >> 6, lane = tid & 63;
    const int c = lane & 15, quad = lane >> 4;
    const int wm = (wave & 1) * 64, wn = (wave >> 1) * 64;

    const int ci0 = (wave * 2 + 0) * 64 + lane;
    const int ci1 = (wave * 2 + 1) * 64 + lane;
    const bf16* ga0 = A  + (size_t)(m0 + (ci0 >> 2)) * K + (ci0 & 3) * 8;
    const bf16* ga1 = A  + (size_t)(m0 + (ci1 >> 2)) * K + (ci1 & 3) * 8;
    const bf16* gb0 = Bt + (size_t)(n0 + (ci0 >> 2)) * K + (ci0 & 3) * 8;
    const bf16* gb1 = Bt + (size_t)(n0 + (ci1 >> 2)) * K + (ci1 & 3) * 8;
    bf16* la0 = As + (wave * 2 + 0) * 512;
    bf16* la1 = As + (wave * 2 + 1) * 512;
    bf16* lb0 = Bs + (wave * 2 + 0) * 512;
    bf16* lb1 = Bs + (wave * 2 + 1) * 512;

    for (int kt = 0; kt < K; kt += 32) {
        async16(ga0 + kt, la0);
        async16(ga1 + kt, la1);
        async16(gb0 + kt, lb0);
        async16(gb1 + kt, lb1);
        __syncthreads();
        bf16x8 af[4], bfr[4];
        #pragma unroll
        for (int i = 0; i < 4; i++)
            af[i] = *(const bf16x8*)(As + (wm + i * 16 + c) * 32 + quad * 8);
        #pragma unroll
        for (int j = 0; j < 4; j++)
            bfr[j] = *(const bf16x8*)(Bs + (wn + j * 16 + c) * 32 + quad * 8);
        #pragma unroll
        for (int i = 0; i < 4; i++)
            #pragma unroll
            for (int j = 0; j < 4; j++)
                acc[i][j] = __builtin_amdgcn_mfma_f32_16x16x32_bf16(af[i], bfr[j], acc[i][j], 0, 0, 0);
        __syncthreads();
    }
}

// ---------------- GEMM 1: qkv = x @ Wqkv + bqkv, scatter to Q/K/Vt ----------------
// Q (pre-scaled by QSCALE), K: [B*H][N][hd] bf16 ; Vt: [B*H][hd][N] bf16

__global__ __launch_bounds__(256) void gemm_qkv(const bf16* __restrict__ A,
                                                const bf16* __restrict__ Bt,
                                                const float* __restrict__ bias,
                                                bf16* __restrict__ Qb,
                                                bf16* __restrict__ Kb,
                                                bf16* __restrict__ Vtb) {
    __shared__ __align__(16) bf16 As[128 * 32];
    __shared__ __align__(16) bf16 Bs[128 * 32];
    f32x4 acc[4][4] = {};
    const int m0 = blockIdx.x * 128, n0 = blockIdx.y * 128;
    gemm_mainloop(A, Bt, 1024, m0, n0, As, Bs, acc);

    const int tid = threadIdx.x;
    const int wave = tid >> 6, lane = tid & 63;
    const int c = lane & 15, quad = lane >> 4;
    const int wm = (wave & 1) * 64, wn = (wave >> 1) * 64;
    const int sel = n0 >> 10;  // 0=Q 1=K 2=V
    bf16* QK = (sel == 0) ? Qb : Kb;
    const float qs = (sel == 0) ? QSCALE : 1.0f;

    #pragma unroll
    for (int j = 0; j < 4; j++) {
        const int nfull = n0 + wn + j * 16 + c;
        const int nmod = nfull & 1023;
        const int h = nmod >> 6, e = nmod & 63;
        const float bv = bias[nfull];
        #pragma unroll
        for (int i = 0; i < 4; i++) {
            const int mbase = m0 + wm + i * 16 + quad * 4;
            const int b = mbase >> 11, t = mbase & 2047;
            if (sel < 2) {
                bf16* dst = QK + (((size_t)(b * 16 + h) * 2048 + t) * 64 + e);
                #pragma unroll
                for (int r = 0; r < 4; r++)
                    dst[(size_t)r * 64] = (bf16)((acc[i][j][r] + bv) * qs);
            } else {
                bf16* dst = Vtb + ((size_t)(b * 16 + h) * 64 + e) * 2048 + t;
                bf16x4 v;
                v.x = (bf16)(acc[i][j][0] + bv);
                v.y = (bf16)(acc[i][j][1] + bv);
                v.z = (bf16)(acc[i][j][2] + bv);
                v.w = (bf16)(acc[i][j][3] + bv);
                *(bf16x4*)dst = v;
            }
        }
    }
}

// ---------------- flash attention (LDS-free operand loads) ----------------
// grid: (64 bh, 16 qt)  — bh in x so all q-tiles of one head share an XCD's L2.
// Each wave handles 32 q rows (2 i-tiles of 16). No __syncthreads in the loop.
// S^T = K·Q^T orientation: softmax rows are per-lane (q = c); P transposed to
// A-operand layout via a small padded per-wave LDS buffer (2-way writes).

__global__ __launch_bounds__(256, 2) void attn_kernel(const bf16* __restrict__ Q,
                                                      const bf16* __restrict__ Kg,
                                                      const bf16* __restrict__ Vt,
                                                      bf16* __restrict__ Out) {
    // per-wave, per-i-tile P buffer: 16 q-rows x 128 keys, row stride 136 (16B-aligned pad)
    __shared__ __align__(16) bf16 Pl[4 * 2 * 16 * 136];  // 34816 B

    const int bh = blockIdx.x, qt = blockIdx.y;
    const int tid = threadIdx.x;
    const int wave = tid >> 6, lane = tid & 63;
    const int c = lane & 15, quad = lane >> 4;

    const bf16* Qb = Q  + (size_t)bh * 2048 * 64;
    const bf16* Kb = Kg + (size_t)bh * 2048 * 64;
    const bf16* Vb = Vt + (size_t)bh * 64 * 2048;
    bf16* pw = Pl + wave * 2 * 16 * 136;

    const int qbase = qt * 128 + wave * 32;

    // Q fragments (B-operand): lane holds Q[q = qbase+i*16+c][d = ks*32+quad*8 ..+8]
    bf16x8 qf[2][2];
    #pragma unroll
    for (int i = 0; i < 2; i++)
        #pragma unroll
        for (int ks = 0; ks < 2; ks++)
            qf[i][ks] = *(const bf16x8*)(Qb + (size_t)(qbase + i * 16 + c) * 64 + ks * 32 + quad * 8);

    float m_i[2] = {-3e38f, -3e38f};
    float l_i[2] = {0.f, 0.f};
    f32x4 o[2][4] = {};

    for (int kv = 0; kv < 16; kv++) {
        const bf16* Kt = Kb + (size_t)kv * 128 * 64;

        // ---- S^T = K·Q^T : s[i][j][r] = S[key = kv*128 + j*16 + quad*4 + r][q = i*16+c] ----
        f32x4 s[2][8] = {};
        #pragma unroll
        for (int j = 0; j < 8; j++) {
            bf16x8 kf0 = *(const bf16x8*)(Kt + (size_t)(j * 16 + c) * 64 + quad * 8);
            bf16x8 kf1 = *(const bf16x8*)(Kt + (size_t)(j * 16 + c) * 64 + 32 + quad * 8);
            #pragma unroll
            for (int i = 0; i < 2; i++) {
                s[i][j] = __builtin_amdgcn_mfma_f32_16x16x32_bf16(kf0, qf[i][0], s[i][j], 0, 0, 0);
                s[i][j] = __builtin_amdgcn_mfma_f32_16x16x32_bf16(kf1, qf[i][1], s[i][j], 0, 0, 0);
            }
        }

        // ---- online softmax: row q = c lives in lanes {c, c+16, c+32, c+48} ----
        #pragma unroll
        for (int i = 0; i < 2; i++) {
            float mx = s[i][0][0];
            #pragma unroll
            for (int j = 0; j < 8; j++)
                #pragma unroll
                for (int r = 0; r < 4; r++) mx = fmaxf(mx, s[i][j][r]);
            mx = fmaxf(mx, __shfl_xor(mx, 16));
            mx = fmaxf(mx, __shfl_xor(mx, 32));
            const float mn = fmaxf(m_i[i], mx);
            const float al = exp2f(m_i[i] - mn);
            m_i[i] = mn;
            float sum = 0.f;
            #pragma unroll
            for (int j = 0; j < 8; j++) {
                #pragma unroll
                for (int r = 0; r < 4; r++) {
                    const float p = exp2f(s[i][j][r] - mn);
                    s[i][j][r] = p;
                    sum += p;
                }
            }
            sum += __shfl_xor(sum, 16);
            sum += __shfl_xor(sum, 32);
            l_i[i] = al * l_i[i] + sum;

            // pack P (bf16x4 along r = 4 consecutive keys) -> padded LDS, 2-way banks
            #pragma unroll
            for (int j = 0; j < 8; j++) {
                bf16x4 pk;
                pk.x = (bf16)s[i][j][0]; pk.y = (bf16)s[i][j][1];
                pk.z = (bf16)s[i][j][2]; pk.w = (bf16)s[i][j][3];
                *(bf16x4*)(pw + (i * 16 + c) * 136 + j * 16 + quad * 4) = pk;
            }

            // rescale O_i : alpha for q-row quad*4+r via lane broadcast
            const float a0 = __shfl(al, quad * 4 + 0);
            const float a1 = __shfl(al, quad * 4 + 1);
            const float a2 = __shfl(al, quad * 4 + 2);
            const float a3 = __shfl(al, quad * 4 + 3);
            #pragma unroll
            for (int n2 = 0; n2 < 4; n2++) {
                o[i][n2][0] *= a0; o[i][n2][1] *= a1;
                o[i][n2][2] *= a2; o[i][n2][3] *= a3;
            }
        }

        // ---- PV: O[q][d] += P[q][key] V[key][d], V^T frags direct from global ----
        #pragma unroll
        for (int h2 = 0; h2 < 2; h2++) {
            #pragma unroll
            for (int ks = 0; ks < 2; ks++) {
                const int gks = h2 * 2 + ks;
                bf16x8 vf[4];
                #pragma unroll
                for (int n2 = 0; n2 < 4; n2++)
                    vf[n2] = *(const bf16x8*)(Vb + (size_t)(n2 * 16 + c) * 2048 + kv * 128 + gks * 32 + quad * 8);
                #pragma unroll
                for (int i = 0; i < 2; i++) {
                    bf16x8 pf = *(const bf16x8*)(pw + (i * 16 + c) * 136 + h2 * 64 + ks * 32 + quad * 8);
                    #pragma unroll
                    for (int n2 = 0; n2 < 4; n2++)
                        o[i][n2] = __builtin_amdgcn_mfma_f32_16x16x32_bf16(pf, vf[n2], o[i][n2], 0, 0, 0);
                }
            }
        }
    }

    // ---- epilogue: O /= l, write token-major bf16 ----
    const int b = bh >> 4, h = bh & 15;
    #pragma unroll
    for (int i = 0; i < 2; i++) {
        const float li0 = __shfl(l_i[i], quad * 4 + 0);
        const float li1 = __shfl(l_i[i], quad * 4 + 1);
        const float li2 = __shfl(l_i[i], quad * 4 + 2);
        const float li3 = __shfl(l_i[i], quad * 4 + 3);
        const float inv[4] = {1.f / li0, 1.f / li1, 1.f / li2, 1.f / li3};
        #pragma unroll
        for (int r = 0; r < 4; r++) {
            const int token = b * 2048 + qt * 128 + wave * 32 + i * 16 + quad * 4 + r;
            #pragma unroll
            for (int n2 = 0; n2 < 4; n2++) {
                const int feat = h * 64 + n2 * 16 + c;
                Out[(size_t)token * 1024 + feat] = (bf16)(o[i][n2][r] * inv[r]);
            }
        }
    }
}

// ---------------- GEMM 2: out = attn_out @ Wproj + bproj (fp32 out) ----------------

__global__ __launch_bounds__(256) void gemm_proj(const bf16* __restrict__ A,
                                                 const bf16* __restrict__ Bt,
                                                 const float* __restrict__ bias,
                                                 float* __restrict__ Out) {
    __shared__ __align__(16) bf16 As[128 * 32];
    __shared__ __align__(16) bf16 Bs[128 * 32];
    f32x4 acc[4][4] = {};
    const int m0 = blockIdx.x * 128, n0 = blockIdx.y * 128;
    gemm_mainloop(A, Bt, 1024, m0, n0, As, Bs, acc);

    const int tid = threadIdx.x;
    const int wave = tid >> 6, lane = tid & 63;
    const int c = lane & 15, quad = lane >> 4;
    const int wm = (wave & 1) * 64, wn = (wave >> 1) * 64;

    #pragma unroll
    for (int j = 0; j < 4; j++) {
        const int nn = n0 + wn + j * 16 + c;
        const float bv = bias[nn];
        #pragma unroll
        for (int i = 0; i < 4; i++) {
            const int m = m0 + wm + i * 16 + quad * 4;
            #pragma unroll
            for (int r = 0; r < 4; r++)
                Out[(size_t)(m + r) * 1024 + nn] = acc[i][j][r] + bv;
        }
    }
}

// ---------------- launch ----------------

extern "C" void kernel_launch(void* const* d_in, const int* in_sizes, int n_in,
                              void* d_out, int out_size, void* d_ws, size_t ws_size,
                              hipStream_t stream) {
    const float* x     = (const float*)d_in[0];
    const float* Wqkv  = (const float*)d_in[1];
    const float* bqkv  = (const float*)d_in[2];
    const float* Wproj = (const float*)d_in[3];
    const float* bproj = (const float*)d_in[4];
    float* out = (float*)d_out;

    char* ws = (char*)d_ws;
    bf16* xb     = (bf16*)(ws);                       // 16,777,216 B
    bf16* wqkvt  = (bf16*)(ws + 16777216);            //  6,291,456 B
    bf16* wprojt = (bf16*)(ws + 23068672);            //  2,097,152 B
    bf16* Qb     = (bf16*)(ws + 25165824);            // 16,777,216 B
    bf16* Kb     = (bf16*)(ws + 41943040);            // 16,777,216 B
    bf16* Vtb    = (bf16*)(ws + 58720256);            // 16,777,216 B
    bf16* attno  = xb;  // reuse: x_bf16 dead after gemm_qkv

    cvt_f32_bf16<<<8192, 256, 0, stream>>>(x, xb, 2097152);
    transpose_cvt<<<dim3(96, 32), dim3(32, 8), 0, stream>>>(Wqkv, wqkvt, 1024, 3072);
    transpose_cvt<<<dim3(32, 32), dim3(32, 8), 0, stream>>>(Wproj, wprojt, 1024, 1024);
    gemm_qkv<<<dim3(64, 24), 256, 0, stream>>>(xb, wqkvt, bqkv, Qb, Kb, Vtb);
    attn_kernel<<<dim3(64, 16), 256, 0, stream>>>(Qb, Kb, Vtb, attno);
    gemm_proj<<<dim3(64, 8), 256, 0, stream>>>(attno, wprojt, bproj, out);
}